// Round 1
// baseline (1123.994 us; speedup 1.0000x reference)
//
#include <hip/hip_runtime.h>
#include <stdint.h>

#define NB 32
#define NS 2048
#define NE 1024   // ENC
#define ND 1024   // DEC
#define NA 1024   // ATT

typedef float f32x4 __attribute__((ext_vector_type(4)));
typedef __bf16 bf16x8 __attribute__((ext_vector_type(8)));
typedef int i32x4 __attribute__((ext_vector_type(4)));
typedef unsigned short u16x4 __attribute__((ext_vector_type(4)));

__device__ __forceinline__ unsigned short f32_bf16(float x){
  unsigned int u = __float_as_uint(x);
  unsigned int r = (u + 0x7fffu + ((u >> 16) & 1u)) >> 16;
  return (unsigned short)r;
}
__device__ __forceinline__ float bf16_f32(unsigned short h){
  return __uint_as_float(((unsigned int)h) << 16);
}
__device__ __forceinline__ float tanh_fast(float x){
  float ax = fabsf(x);
  float e = __expf(-2.0f * ax);
  float t = (1.0f - e) * __builtin_amdgcn_rcpf(1.0f + e);
  return x < 0.0f ? -t : t;
}

// ---------------- kernel 0: split W_e2a (f32) -> hi/lo bf16 ----------------
__global__ __launch_bounds__(256) void split_w_kernel(
    const float* __restrict__ W, unsigned short* __restrict__ hi,
    unsigned short* __restrict__ lo)
{
  int i = (blockIdx.x * 256 + threadIdx.x) * 4;
  f32x4 w = *reinterpret_cast<const f32x4*>(W + i);
  u16x4 h, l;
  #pragma unroll
  for (int j = 0; j < 4; ++j){
    unsigned short hh = f32_bf16(w[j]);
    h[j] = hh;
    l[j] = f32_bf16(w[j] - bf16_f32(hh));
  }
  *reinterpret_cast<u16x4*>(hi + i) = h;
  *reinterpret_cast<u16x4*>(lo + i) = l;
}

// ---------------- kernel 1: V[b][a] = sum_d q[b][d]*W_d2a[a][d] (f32) ------
__global__ __launch_bounds__(256) void v_kernel(
    const float* __restrict__ q, const float* __restrict__ Wd,
    float* __restrict__ V)
{
  int gw = blockIdx.x * 4 + (threadIdx.x >> 6);
  int l = threadIdx.x & 63;
  int b = gw >> 10, a = gw & 1023;
  const float* qp = q + b * ND;
  const float* wp = Wd + (size_t)a * ND;
  float s = 0.0f;
  #pragma unroll
  for (int c = 0; c < 4; ++c){
    int off = c * 256 + l * 4;
    f32x4 q4 = *reinterpret_cast<const f32x4*>(qp + off);
    f32x4 w4 = *reinterpret_cast<const f32x4*>(wp + off);
    s += q4[0]*w4[0] + q4[1]*w4[1] + q4[2]*w4[2] + q4[3]*w4[3];
  }
  #pragma unroll
  for (int off = 1; off < 64; off <<= 1) s += __shfl_xor(s, off, 64);
  if (l == 0) V[gw] = s;
}

// ---------------- kernel 2: fused U=keys@We^T, e = sum_a tanh(U+V)*vw ------
// 2048 blocks x 512 threads (8 waves). Block = 32 rows of flattened [B*S].
// Wave w owns N-slice [w*128, w*128+128). bf16x2-split: 3 MFMAs per tile.
__global__ __launch_bounds__(512) void score_kernel(
    const float* __restrict__ keys,
    const unsigned short* __restrict__ Whi,
    const unsigned short* __restrict__ Wlo,
    const float* __restrict__ Vb,
    const float* __restrict__ vw,
    float* __restrict__ e_out)
{
  __shared__ __align__(16) unsigned short Ahi[32 * 128];
  __shared__ __align__(16) unsigned short Alo[32 * 128];
  __shared__ float ebuf[8][32];

  const int t = threadIdx.x;
  const int w = t >> 6;
  const int l = t & 63;
  const int l15 = l & 15;
  const int lg = l >> 4;
  const int row0 = blockIdx.x * 32;
  const int b = row0 >> 11;
  const int nb = w << 7;

  f32x4 acc[2][8];
  #pragma unroll
  for (int mf = 0; mf < 2; ++mf)
    #pragma unroll
    for (int nf = 0; nf < 8; ++nf)
      acc[mf][nf] = (f32x4)0.0f;

  const int sr = t >> 4;   // staging row 0..31
  const int sq = t & 15;   // staging quad
  const float* kbase = keys + (size_t)(row0 + sr) * NE;

  for (int kt = 0; kt < 8; ++kt){
    __syncthreads();
    // stage keys f32 [32][128] -> bf16 hi/lo LDS with XOR-swizzle on 16B blocks
    #pragma unroll
    for (int half = 0; half < 2; ++half){
      int c = sq * 4 + half * 64;
      f32x4 v = *reinterpret_cast<const f32x4*>(kbase + kt * 128 + c);
      u16x4 h, lo4;
      #pragma unroll
      for (int j = 0; j < 4; ++j){
        unsigned short hh = f32_bf16(v[j]);
        h[j] = hh;
        lo4[j] = f32_bf16(v[j] - bf16_f32(hh));
      }
      int idx = sr * 128 + ((((c >> 3) ^ (sr & 7))) << 3) + (c & 7);
      *reinterpret_cast<u16x4*>(&Ahi[idx]) = h;
      *reinterpret_cast<u16x4*>(&Alo[idx]) = lo4;
    }
    __syncthreads();

    #pragma unroll
    for (int ks = 0; ks < 4; ++ks){
      bf16x8 ah[2], al[2];
      #pragma unroll
      for (int mf = 0; mf < 2; ++mf){
        int row = (mf << 4) + l15;
        int idx = row * 128 + ((((ks << 2) + lg) ^ (row & 7)) << 3);
        ah[mf] = __builtin_bit_cast(bf16x8, *reinterpret_cast<const i32x4*>(&Ahi[idx]));
        al[mf] = __builtin_bit_cast(bf16x8, *reinterpret_cast<const i32x4*>(&Alo[idx]));
      }
      const int kg = (kt << 7) + (ks << 5) + (lg << 3);
      #pragma unroll
      for (int nf = 0; nf < 8; ++nf){
        const size_t woff = (size_t)(nb + (nf << 4) + l15) * NE + kg;
        bf16x8 bh = __builtin_bit_cast(bf16x8, *reinterpret_cast<const i32x4*>(Whi + woff));
        bf16x8 bl = __builtin_bit_cast(bf16x8, *reinterpret_cast<const i32x4*>(Wlo + woff));
        #pragma unroll
        for (int mf = 0; mf < 2; ++mf){
          acc[mf][nf] = __builtin_amdgcn_mfma_f32_16x16x32_bf16(ah[mf], bh, acc[mf][nf], 0, 0, 0);
          acc[mf][nf] = __builtin_amdgcn_mfma_f32_16x16x32_bf16(ah[mf], bl, acc[mf][nf], 0, 0, 0);
          acc[mf][nf] = __builtin_amdgcn_mfma_f32_16x16x32_bf16(al[mf], bh, acc[mf][nf], 0, 0, 0);
        }
      }
    }
  }

  // epilogue: e_partial[row] = sum_n tanh(U + V[b][n]) * vw[n]
  float er[8];
  #pragma unroll
  for (int j = 0; j < 8; ++j) er[j] = 0.0f;
  #pragma unroll
  for (int nf = 0; nf < 8; ++nf){
    int n = nb + (nf << 4) + l15;
    float Vl  = Vb[b * NA + n];
    float vwl = vw[n];
    #pragma unroll
    for (int mf = 0; mf < 2; ++mf)
      #pragma unroll
      for (int i = 0; i < 4; ++i){
        float u = acc[mf][nf][i] + Vl;
        er[(mf << 2) + i] += tanh_fast(u) * vwl;
      }
  }
  #pragma unroll
  for (int j = 0; j < 8; ++j){
    #pragma unroll
    for (int off = 1; off < 16; off <<= 1)
      er[j] += __shfl_xor(er[j], off, 64);
  }
  if (l15 == 0){
    #pragma unroll
    for (int mf = 0; mf < 2; ++mf)
      #pragma unroll
      for (int i = 0; i < 4; ++i)
        ebuf[w][(mf << 4) + (lg << 2) + i] = er[(mf << 2) + i];
  }
  __syncthreads();
  if (t < 32){
    float s = 0.0f;
    #pragma unroll
    for (int w2 = 0; w2 < 8; ++w2) s += ebuf[w2][t];
    e_out[row0 + t] = s;
  }
}

// ---------------- kernel 3: softmax over S per batch -----------------------
__global__ __launch_bounds__(256) void softmax_kernel(
    const float* __restrict__ e, float* __restrict__ a)
{
  __shared__ float red[4];
  const int b = blockIdx.x;
  const int t = threadIdx.x;
  const int l = t & 63, w = t >> 6;
  const float* ep = e + b * NS + t * 8;
  float v[8];
  *reinterpret_cast<f32x4*>(&v[0]) = *reinterpret_cast<const f32x4*>(ep);
  *reinterpret_cast<f32x4*>(&v[4]) = *reinterpret_cast<const f32x4*>(ep + 4);

  float m = v[0];
  #pragma unroll
  for (int j = 1; j < 8; ++j) m = fmaxf(m, v[j]);
  #pragma unroll
  for (int off = 1; off < 64; off <<= 1) m = fmaxf(m, __shfl_xor(m, off, 64));
  if (l == 0) red[w] = m;
  __syncthreads();
  m = fmaxf(fmaxf(red[0], red[1]), fmaxf(red[2], red[3]));
  __syncthreads();

  float ex[8];
  float s = 0.0f;
  #pragma unroll
  for (int j = 0; j < 8; ++j){ ex[j] = __expf(v[j] - m); s += ex[j]; }
  #pragma unroll
  for (int off = 1; off < 64; off <<= 1) s += __shfl_xor(s, off, 64);
  if (l == 0) red[w] = s;
  __syncthreads();
  s = red[0] + red[1] + red[2] + red[3];
  float inv = 1.0f / s;

  float o[8];
  #pragma unroll
  for (int j = 0; j < 8; ++j) o[j] = ex[j] * inv;
  float* ap = a + b * NS + t * 8;
  *reinterpret_cast<f32x4*>(ap)     = *reinterpret_cast<f32x4*>(&o[0]);
  *reinterpret_cast<f32x4*>(ap + 4) = *reinterpret_cast<f32x4*>(&o[4]);
}

// ---------------- kernel 4a: partial context over s-chunks -----------------
__global__ __launch_bounds__(256) void ctx_partial_kernel(
    const float* __restrict__ a, const float* __restrict__ keys,
    float* __restrict__ part)
{
  const int bid = blockIdx.x;           // 0..255
  const int b = bid >> 3, sc = bid & 7;
  const int t = threadIdx.x;
  f32x4 accv = (f32x4)0.0f;
  const float* kp = keys + (size_t)(b * NS + sc * 256) * NE + t * 4;
  const float* ap = a + b * NS + sc * 256;
  for (int si = 0; si < 256; ++si){
    float as = ap[si];
    f32x4 k4 = *reinterpret_cast<const f32x4*>(kp + (size_t)si * NE);
    accv += as * k4;
  }
  *reinterpret_cast<f32x4*>(part + (size_t)bid * NE + t * 4) = accv;
}

// ---------------- kernel 4b: deterministic reduce of partials --------------
__global__ __launch_bounds__(256) void ctx_reduce_kernel(
    const float* __restrict__ part, float* __restrict__ out)
{
  const int b = blockIdx.x;
  const int t = threadIdx.x;
  f32x4 s = (f32x4)0.0f;
  #pragma unroll
  for (int sc = 0; sc < 8; ++sc)
    s += *reinterpret_cast<const f32x4*>(part + (size_t)((b << 3) + sc) * NE + t * 4);
  *reinterpret_cast<f32x4*>(out + b * NE + t * 4) = s;
}

extern "C" void kernel_launch(void* const* d_in, const int* in_sizes, int n_in,
                              void* d_out, int out_size, void* d_ws, size_t ws_size,
                              hipStream_t stream)
{
  const float* keys = (const float*)d_in[0];
  const float* q    = (const float*)d_in[1];
  const float* We   = (const float*)d_in[2];
  const float* Wd   = (const float*)d_in[3];
  const float* vw   = (const float*)d_in[4];
  float* out = (float*)d_out;

  char* ws = (char*)d_ws;
  unsigned short* Whi = (unsigned short*)(ws);
  unsigned short* Wlo = (unsigned short*)(ws + (size_t)NA * NE * 2);
  float* Vb   = (float*)(ws + (size_t)NA * NE * 4);
  float* e    = (float*)(ws + (size_t)NA * NE * 4 + (size_t)NB * NA * 4);
  float* a    = (float*)(ws + (size_t)NA * NE * 4 + (size_t)NB * NA * 4 + (size_t)NB * NS * 4);
  float* part = (float*)(ws + (size_t)NA * NE * 4 + (size_t)NB * NA * 4 + 2 * (size_t)NB * NS * 4);

  split_w_kernel<<<(NA * NE) / 1024, 256, 0, stream>>>(We, Whi, Wlo);
  v_kernel<<<(NB * NA) / 4, 256, 0, stream>>>(q, Wd, Vb);
  score_kernel<<<(NB * NS) / 32, 512, 0, stream>>>(keys, Whi, Wlo, Vb, vw, e);
  softmax_kernel<<<NB, 256, 0, stream>>>(e, a);
  ctx_partial_kernel<<<NB * 8, 256, 0, stream>>>(a, keys, part);
  ctx_reduce_kernel<<<NB, 256, 0, stream>>>(part, out);
}

// Round 2
// 479.480 us; speedup vs baseline: 2.3442x; 2.3442x over previous
//
#include <hip/hip_runtime.h>
#include <stdint.h>

#define NB 32
#define NS 2048
#define NE 1024   // ENC
#define ND 1024   // DEC
#define NA 1024   // ATT
#define MROWS (NB * NS)   // 65536

typedef float f32x4 __attribute__((ext_vector_type(4)));
typedef __bf16 bf16x8 __attribute__((ext_vector_type(8)));
typedef int i32x4 __attribute__((ext_vector_type(4)));
typedef unsigned int u32x2 __attribute__((ext_vector_type(2)));
typedef unsigned short u16x4 __attribute__((ext_vector_type(4)));

typedef __attribute__((address_space(3))) unsigned int lds_u32;
typedef __attribute__((address_space(1))) unsigned int glb_u32;

__device__ __forceinline__ unsigned short f32_bf16(float x){
  unsigned int u = __float_as_uint(x);
  unsigned int r = (u + 0x7fffu + ((u >> 16) & 1u)) >> 16;
  return (unsigned short)r;
}
__device__ __forceinline__ float bf16_f32(unsigned short h){
  return __uint_as_float(((unsigned int)h) << 16);
}
__device__ __forceinline__ float tanh_fast(float x){
  float ax = fabsf(x);
  float e = __expf(-2.0f * ax);
  float t = (1.0f - e) * __builtin_amdgcn_rcpf(1.0f + e);
  return x < 0.0f ? -t : t;
}
__device__ __forceinline__ void gload_lds16(const void* g, void* l){
  __builtin_amdgcn_global_load_lds((const glb_u32*)g, (lds_u32*)l, 16, 0, 0);
}

// ---------------- kernel 0: split W_e2a (f32) -> hi/lo bf16 ----------------
__global__ __launch_bounds__(256) void split_w_kernel(
    const float* __restrict__ W, unsigned short* __restrict__ hi,
    unsigned short* __restrict__ lo)
{
  int i = (blockIdx.x * 256 + threadIdx.x) * 4;
  f32x4 w = *reinterpret_cast<const f32x4*>(W + i);
  u16x4 h, l;
  #pragma unroll
  for (int j = 0; j < 4; ++j){
    unsigned short hh = f32_bf16(w[j]);
    h[j] = hh;
    l[j] = f32_bf16(w[j] - bf16_f32(hh));
  }
  *reinterpret_cast<u16x4*>(hi + i) = h;
  *reinterpret_cast<u16x4*>(lo + i) = l;
}

// ---------------- kernel 1: V[b][a] = sum_d q[b][d]*W_d2a[a][d] ------------
__global__ __launch_bounds__(256) void v_kernel(
    const float* __restrict__ q, const float* __restrict__ Wd,
    float* __restrict__ V)
{
  int gw = blockIdx.x * 4 + (threadIdx.x >> 6);
  int l = threadIdx.x & 63;
  int b = gw >> 10, a = gw & 1023;
  const float* qp = q + b * ND;
  const float* wp = Wd + (size_t)a * ND;
  float s = 0.0f;
  #pragma unroll
  for (int c = 0; c < 4; ++c){
    int off = c * 256 + l * 4;
    f32x4 q4 = *reinterpret_cast<const f32x4*>(qp + off);
    f32x4 w4 = *reinterpret_cast<const f32x4*>(wp + off);
    s += q4[0]*w4[0] + q4[1]*w4[1] + q4[2]*w4[2] + q4[3]*w4[3];
  }
  #pragma unroll
  for (int off = 1; off < 64; off <<= 1) s += __shfl_xor(s, off, 64);
  if (l == 0) V[gw] = s;
}

// ---------------- kernel 2: tiled GEMM + partial-e epilogue ----------------
// Grid 4096 = 512 M-tiles (BM=128) x 8 N-chunks (BN=128). 256 thr = 4 waves
// (2Mx2N), per-wave 64x64 (acc[4][4] of 16x16x32 bf16 MFMA, 3-product split).
// BK=64, single-buffer LDS 64KB, 2-barrier loop. B via global_load_lds with
// inverse-swizzled source; A reg-staged f32->bf16 hi/lo with XOR-swizzle.
__global__ __launch_bounds__(256) void score_kernel(
    const float* __restrict__ keys,
    const unsigned short* __restrict__ Whi,
    const unsigned short* __restrict__ Wlo,
    const float* __restrict__ Vb,
    const float* __restrict__ vw,
    float* __restrict__ e_part)
{
  __shared__ __align__(16) unsigned short Ahi[128 * 64];
  __shared__ __align__(16) unsigned short Alo[128 * 64];
  __shared__ __align__(16) unsigned short Bhi[128 * 64];
  __shared__ __align__(16) unsigned short Blo[128 * 64];
  __shared__ float ebuf[4 * 64];

  const int t = threadIdx.x;
  const int w = t >> 6, l = t & 63;
  const int l15 = l & 15, lg = l >> 4;
  const int wr = w >> 1, wc = w & 1;

  // XCD swizzle: co-locate the 8 N-chunks of one M-tile on one XCD.
  const int orig = blockIdx.x;
  const int xcd = orig & 7;
  const int s = orig >> 3;
  const int mtile = ((s >> 3) << 3) | xcd;   // bijective over [0,512)
  const int nchunk = s & 7;
  const int row0 = mtile << 7;               // 128 rows per tile
  const int nb0 = nchunk << 7;
  const int b = row0 >> 11;

  f32x4 acc[4][4];
  #pragma unroll
  for (int mf = 0; mf < 4; ++mf)
    #pragma unroll
    for (int nf = 0; nf < 4; ++nf)
      acc[mf][nf] = (f32x4)0.0f;

  const int arow_t = t >> 4;        // 0..15
  const int ak = (t & 15) << 2;     // 0..60 (4 f32 per thread per pass)
  const int ablk = ak >> 3;
  const int alow = ak & 7;

  for (int kt = 0; kt < NE / 64; ++kt){
    __syncthreads();

    // --- A global loads first (their converts depend on them) ---
    f32x4 av[8];
    #pragma unroll
    for (int p = 0; p < 8; ++p){
      int row = (p << 4) + arow_t;
      av[p] = *reinterpret_cast<const f32x4*>(
          keys + (size_t)(row0 + row) * NE + (kt << 6) + ak);
    }

    // --- B: global_load_lds, 4 chunks of 1KB per wave per component ---
    #pragma unroll
    for (int c = 0; c < 4; ++c){
      const int chunk = (w << 2) + c;
      const int L = (chunk << 10) + (l << 4);      // byte offset in 16KB tile
      const int brow = L >> 7;
      const int blk = ((L >> 4) & 7) ^ (brow & 7); // inverse swizzle on source
      const size_t goff = (size_t)(nb0 + brow) * NE + (kt << 6) + (blk << 3);
      gload_lds16(Whi + goff, &Bhi[chunk << 9]);
      gload_lds16(Wlo + goff, &Blo[chunk << 9]);
    }

    // --- A convert + swizzled ds_write ---
    #pragma unroll
    for (int p = 0; p < 8; ++p){
      int row = (p << 4) + arow_t;
      unsigned int hp[2], lp[2];
      #pragma unroll
      for (int g = 0; g < 2; ++g){
        unsigned int u0 = __float_as_uint(av[p][g * 2]);
        unsigned int u1 = __float_as_uint(av[p][g * 2 + 1]);
        unsigned short h0 = f32_bf16(av[p][g * 2]);
        unsigned short h1 = f32_bf16(av[p][g * 2 + 1]);
        unsigned short l0 = f32_bf16(av[p][g * 2] - bf16_f32(h0));
        unsigned short l1 = f32_bf16(av[p][g * 2 + 1] - bf16_f32(h1));
        hp[g] = (unsigned int)h0 | ((unsigned int)h1 << 16);
        lp[g] = (unsigned int)l0 | ((unsigned int)l1 << 16);
        (void)u0; (void)u1;
      }
      int idx = (row << 6) + ((ablk ^ (row & 7)) << 3) + alow;
      *reinterpret_cast<u32x2*>(&Ahi[idx]) = *reinterpret_cast<u32x2*>(hp);
      *reinterpret_cast<u32x2*>(&Alo[idx]) = *reinterpret_cast<u32x2*>(lp);
    }

    __syncthreads();

    // --- compute: 2 k-slices of 32, 48 MFMAs each ---
    #pragma unroll
    for (int ks = 0; ks < 2; ++ks){
      bf16x8 ah[4], al4[4], bh[4], bl4[4];
      #pragma unroll
      for (int mf = 0; mf < 4; ++mf){
        int row = (wr << 6) + (mf << 4) + l15;
        int idx = (row << 6) + ((((ks << 2) + lg) ^ (row & 7)) << 3);
        ah[mf]  = __builtin_bit_cast(bf16x8, *reinterpret_cast<const i32x4*>(&Ahi[idx]));
        al4[mf] = __builtin_bit_cast(bf16x8, *reinterpret_cast<const i32x4*>(&Alo[idx]));
      }
      #pragma unroll
      for (int nf = 0; nf < 4; ++nf){
        int row = (wc << 6) + (nf << 4) + l15;
        int idx = (row << 6) + ((((ks << 2) + lg) ^ (row & 7)) << 3);
        bh[nf]  = __builtin_bit_cast(bf16x8, *reinterpret_cast<const i32x4*>(&Bhi[idx]));
        bl4[nf] = __builtin_bit_cast(bf16x8, *reinterpret_cast<const i32x4*>(&Blo[idx]));
      }
      #pragma unroll
      for (int nf = 0; nf < 4; ++nf)
        #pragma unroll
        for (int mf = 0; mf < 4; ++mf){
          acc[mf][nf] = __builtin_amdgcn_mfma_f32_16x16x32_bf16(ah[mf],  bh[nf],  acc[mf][nf], 0, 0, 0);
          acc[mf][nf] = __builtin_amdgcn_mfma_f32_16x16x32_bf16(ah[mf],  bl4[nf], acc[mf][nf], 0, 0, 0);
          acc[mf][nf] = __builtin_amdgcn_mfma_f32_16x16x32_bf16(al4[mf], bh[nf],  acc[mf][nf], 0, 0, 0);
        }
    }
  }

  // --- epilogue: partial e over this block's 128 N-cols ---
  float er[16];
  #pragma unroll
  for (int j = 0; j < 16; ++j) er[j] = 0.0f;
  #pragma unroll
  for (int nf = 0; nf < 4; ++nf){
    int n = nb0 + (wc << 6) + (nf << 4) + l15;
    float Vl  = Vb[b * NA + n];
    float vwl = vw[n];
    #pragma unroll
    for (int mf = 0; mf < 4; ++mf)
      #pragma unroll
      for (int i = 0; i < 4; ++i){
        float u = acc[mf][nf][i] + Vl;
        er[(mf << 2) + i] += tanh_fast(u) * vwl;
      }
  }
  #pragma unroll
  for (int j = 0; j < 16; ++j){
    #pragma unroll
    for (int off = 1; off < 16; off <<= 1)
      er[j] += __shfl_xor(er[j], off, 64);
  }
  if (l15 == 0){
    #pragma unroll
    for (int mf = 0; mf < 4; ++mf)
      #pragma unroll
      for (int i = 0; i < 4; ++i)
        ebuf[(w << 6) + (mf << 4) + (lg << 2) + i] = er[(mf << 2) + i];
  }
  __syncthreads();
  if (t < 128){
    int wr2 = t >> 6, r = t & 63;
    float v = ebuf[((wr2 << 1) << 6) + r] + ebuf[(((wr2 << 1) + 1) << 6) + r];
    e_part[(size_t)nchunk * MROWS + row0 + t] = v;
  }
}

// ---------------- kernel 3: sum partials + softmax over S ------------------
__global__ __launch_bounds__(256) void softmax_kernel(
    const float* __restrict__ e_part, float* __restrict__ a)
{
  __shared__ float red[4];
  const int b = blockIdx.x;
  const int t = threadIdx.x;
  const int l = t & 63, w = t >> 6;
  const float* ep = e_part + b * NS + t * 8;
  float v[8];
  #pragma unroll
  for (int j = 0; j < 8; ++j) v[j] = 0.0f;
  #pragma unroll
  for (int c = 0; c < 8; ++c){
    f32x4 x0 = *reinterpret_cast<const f32x4*>(ep + (size_t)c * MROWS);
    f32x4 x1 = *reinterpret_cast<const f32x4*>(ep + (size_t)c * MROWS + 4);
    #pragma unroll
    for (int j = 0; j < 4; ++j){ v[j] += x0[j]; v[4 + j] += x1[j]; }
  }

  float m = v[0];
  #pragma unroll
  for (int j = 1; j < 8; ++j) m = fmaxf(m, v[j]);
  #pragma unroll
  for (int off = 1; off < 64; off <<= 1) m = fmaxf(m, __shfl_xor(m, off, 64));
  if (l == 0) red[w] = m;
  __syncthreads();
  m = fmaxf(fmaxf(red[0], red[1]), fmaxf(red[2], red[3]));
  __syncthreads();

  float ex[8];
  float ssum = 0.0f;
  #pragma unroll
  for (int j = 0; j < 8; ++j){ ex[j] = __expf(v[j] - m); ssum += ex[j]; }
  #pragma unroll
  for (int off = 1; off < 64; off <<= 1) ssum += __shfl_xor(ssum, off, 64);
  if (l == 0) red[w] = ssum;
  __syncthreads();
  ssum = red[0] + red[1] + red[2] + red[3];
  float inv = 1.0f / ssum;

  float o[8];
  #pragma unroll
  for (int j = 0; j < 8; ++j) o[j] = ex[j] * inv;
  float* ap = a + b * NS + t * 8;
  *reinterpret_cast<f32x4*>(ap)     = *reinterpret_cast<f32x4*>(&o[0]);
  *reinterpret_cast<f32x4*>(ap + 4) = *reinterpret_cast<f32x4*>(&o[4]);
}

// ---------------- kernel 4a: partial context over s-chunks -----------------
__global__ __launch_bounds__(256) void ctx_partial_kernel(
    const float* __restrict__ a, const float* __restrict__ keys,
    float* __restrict__ part)
{
  const int bid = blockIdx.x;           // 0..255
  const int b = bid >> 3, sc = bid & 7;
  const int t = threadIdx.x;
  f32x4 accv = (f32x4)0.0f;
  const float* kp = keys + (size_t)(b * NS + sc * 256) * NE + t * 4;
  const float* ap = a + b * NS + sc * 256;
  for (int si = 0; si < 256; ++si){
    float as = ap[si];
    f32x4 k4 = *reinterpret_cast<const f32x4*>(kp + (size_t)si * NE);
    accv += as * k4;
  }
  *reinterpret_cast<f32x4*>(part + (size_t)bid * NE + t * 4) = accv;
}

// ---------------- kernel 4b: deterministic reduce of partials --------------
__global__ __launch_bounds__(256) void ctx_reduce_kernel(
    const float* __restrict__ part, float* __restrict__ out)
{
  const int b = blockIdx.x;
  const int t = threadIdx.x;
  f32x4 s = (f32x4)0.0f;
  #pragma unroll
  for (int sc = 0; sc < 8; ++sc)
    s += *reinterpret_cast<const f32x4*>(part + (size_t)((b << 3) + sc) * NE + t * 4);
  *reinterpret_cast<f32x4*>(out + b * NE + t * 4) = s;
}

extern "C" void kernel_launch(void* const* d_in, const int* in_sizes, int n_in,
                              void* d_out, int out_size, void* d_ws, size_t ws_size,
                              hipStream_t stream)
{
  const float* keys = (const float*)d_in[0];
  const float* q    = (const float*)d_in[1];
  const float* We   = (const float*)d_in[2];
  const float* Wd   = (const float*)d_in[3];
  const float* vw   = (const float*)d_in[4];
  float* out = (float*)d_out;

  char* ws = (char*)d_ws;
  unsigned short* Whi = (unsigned short*)(ws);                    // 2 MB
  unsigned short* Wlo = (unsigned short*)(ws + (size_t)2097152);  // 2 MB
  float* Vb     = (float*)(ws + (size_t)4194304);                 // 128 KB
  float* e_part = (float*)(ws + (size_t)4325376);                 // 2 MB
  float* a      = (float*)(ws + (size_t)6422528);                 // 256 KB
  float* part   = e_part;  // aliased: e_part dead after softmax

  split_w_kernel<<<(NA * NE) / 1024, 256, 0, stream>>>(We, Whi, Wlo);
  v_kernel<<<(NB * NA) / 4, 256, 0, stream>>>(q, Wd, Vb);
  score_kernel<<<4096, 256, 0, stream>>>(keys, Whi, Wlo, Vb, vw, e_part);
  softmax_kernel<<<NB, 256, 0, stream>>>(e_part, a);
  ctx_partial_kernel<<<NB * 8, 256, 0, stream>>>(a, keys, part);
  ctx_reduce_kernel<<<NB, 256, 0, stream>>>(part, out);
}